// Round 1
// baseline (30248.703 us; speedup 1.0000x reference)
//
#include <hip/hip_runtime.h>
#include <hip/hip_bf16.h>
#include <stdint.h>

// Dims
#define B64    64
#define TENC   200
#define ENCD   512
#define MELD   80
#define PRED   256
#define ATTND  128
#define ARNN_  1024
#define DRNN_  1024
#define FILT_  32
#define KCONV  31
#define STEPS  200
#define KA     1792   // p(256) + ctx(512) + ah(1024)
#define KD     2560   // ah(1024) + ctx(512) + dh(1024)

using bf16 = __bf16;
typedef __bf16 bf16x8 __attribute__((ext_vector_type(8)));
typedef float  f32x4  __attribute__((ext_vector_type(4)));

#define MFMA16(a,b,c) __builtin_amdgcn_mfma_f32_16x16x32_bf16((a),(b),(c),0,0,0)

__device__ __forceinline__ float sigf(float x){ return 1.f/(1.f+__expf(-x)); }
__device__ __forceinline__ float tanhf_(float x){
  float ax = fabsf(x);
  float e  = __expf(-2.f*ax);
  float t  = (1.f-e)/(1.f+e);
  return x < 0.f ? -t : t;
}

// ---------------- prologue conversion kernels ----------------
__global__ void cvt_kernel(const float* __restrict__ s, bf16* __restrict__ d, int n){
  int i = blockIdx.x*256 + threadIdx.x;
  if (i < n) d[i] = (bf16)s[i];
}
__global__ void cvt_pad_kernel(const float* __restrict__ s, bf16* __restrict__ d,
                               int rows, int cin, int cout){
  int i = blockIdx.x*256 + threadIdx.x;
  if (i >= rows*cout) return;
  int r = i / cout, c = i % cout;
  d[i] = (bf16)(c < cin ? s[(size_t)r*cin + c] : 0.f);
}
__global__ void cat_cvt_kernel(const float* __restrict__ s1, int c1,
                               const float* __restrict__ s2, int c2,
                               bf16* __restrict__ d, int rows){
  int C = c1 + c2;
  int i = blockIdx.x*256 + threadIdx.x;
  if (i >= rows*C) return;
  int r = i / C, c = i % C;
  float v = (c < c1) ? s1[(size_t)r*c1 + c] : s2[(size_t)r*c2 + (c - c1)];
  d[i] = (bf16)v;
}
__global__ void build_wmelcat(const float* __restrict__ Wmel, const float* __restrict__ Wstop,
                              bf16* __restrict__ d){
  int i = blockIdx.x*256 + threadIdx.x;
  if (i >= 176*1536) return;
  int r = i / 1536, c = i % 1536;
  float v = (r < 160) ? Wmel[(size_t)r*1536 + c] : (r == 160 ? Wstop[c] : 0.f);
  d[i] = (bf16)v;
}
__global__ void build_misc(const float* biha, const float* bhha, float* biasa,
                           const float* bihd, const float* bhhd, float* biasd,
                           const float* bmel, const float* bstop, float* bias176){
  int i = blockIdx.x*256 + threadIdx.x;
  if (i < 4096) biasa[i] = biha[i] + bhha[i];
  else if (i < 8192) { int j = i-4096; biasd[j] = bihd[j] + bhhd[j]; }
  else if (i < 8192+176) {
    int j = i - 8192;
    bias176[j] = (j < 160) ? bmel[j] : (j == 160 ? bstop[0] : 0.f);
  }
}
// dec_in (teacher forcing): row = s*64+b (200x64), 96 cols (80 real + 16 zero-pad)
__global__ void build_decin(const float* __restrict__ inp, bf16* __restrict__ d){
  int i = blockIdx.x*256 + threadIdx.x;
  if (i >= 12800*96) return;
  int row = i / 96, c = i % 96;
  int s = row >> 6, b = row & 63;
  float v = 0.f;
  if (c < 80 && s > 0) v = inp[((size_t)b*400 + (2*s - 1))*80 + c];
  d[i] = (bf16)v;
}

// ---------------- generic MFMA GEMM: C[m,n] = act(sum_k A[m,k]*B[n,k] + bias[n]) ----
// wave tile 64(M) x 16(N); 4 waves / block
template<int ACT, int OBF>
__global__ __launch_bounds__(256)
void gemm_k(const bf16* __restrict__ A, const bf16* __restrict__ Bm,
            const float* __restrict__ bias, float* __restrict__ Cf,
            bf16* __restrict__ Cb, int M, int N, int K, int MT)
{
  int wid = blockIdx.x*4 + (threadIdx.x >> 6);
  if (wid >= MT*(N >> 4)) return;
  int wm = wid % MT, wn = wid / MT;
  int l = threadIdx.x & 63, lo = l & 15, hi = l >> 4;
  const bf16* Bp = Bm + (size_t)(wn*16 + lo)*K + hi*8;
  const bf16* Ap = A  + (size_t)(wm*64 + lo)*K + hi*8;
  f32x4 acc0 = {0,0,0,0}, acc1 = {0,0,0,0}, acc2 = {0,0,0,0}, acc3 = {0,0,0,0};
  for (int k = 0; k < K; k += 32){
    bf16x8 bb = *(const bf16x8*)(Bp + k);
    bf16x8 a0 = *(const bf16x8*)(Ap + k);
    bf16x8 a1 = *(const bf16x8*)(Ap + (size_t)16*K + k);
    bf16x8 a2 = *(const bf16x8*)(Ap + (size_t)32*K + k);
    bf16x8 a3 = *(const bf16x8*)(Ap + (size_t)48*K + k);
    acc0 = MFMA16(a0, bb, acc0);
    acc1 = MFMA16(a1, bb, acc1);
    acc2 = MFMA16(a2, bb, acc2);
    acc3 = MFMA16(a3, bb, acc3);
  }
  int n = wn*16 + lo;
  float bv = bias ? bias[n] : 0.f;
  int m0 = wm*64 + hi*4;
  #pragma unroll
  for (int mt = 0; mt < 4; ++mt){
    f32x4 av = (mt==0)?acc0:(mt==1)?acc1:(mt==2)?acc2:acc3;
    #pragma unroll
    for (int r = 0; r < 4; ++r){
      float v = av[r] + bv;
      if (ACT) v = fmaxf(v, 0.f);
      size_t idx = (size_t)(m0 + mt*16 + r)*N + n;
      if (OBF) Cb[idx] = (bf16)v; else Cf[idx] = v;
    }
  }
}

// ---------------- per-step: attn-LSTM gates GEMM + cell update -------------------
// 256 blocks x 64 thr. Block = 4 units x 4 gates (16 B-rows), M=64 batches, K=1792.
// B-row for lane col `lo`: gate=(lo>>2), unit=u0+(lo&3).
__global__ __launch_bounds__(64)
void attn_step(const bf16* __restrict__ pAll,   // p for this step: 64 x 256
               const bf16* __restrict__ AaR,    // read act: 64 x 1536 = [ctx | ah]
               const bf16* __restrict__ W,      // 4096 x 1792 = [Wih_a | Whh_a]
               const float* __restrict__ bias,  // 4096 (bih+bhh)
               float* __restrict__ cell,        // ac 64 x 1024
               bf16* __restrict__ AaW_h,        // write ah: AaW + 512 (stride 1536)
               bf16* __restrict__ AdR_h)        // write ah: Adec cur (stride 2560)
{
  const int tid = threadIdx.x;
  const int lo = tid & 15, hi = tid >> 4;
  const int u0 = blockIdx.x * 4;
  const int gate = lo >> 2, ur = lo & 3;
  const bf16* Bp = W + (size_t)(gate*1024 + u0 + ur)*KA + hi*8;
  f32x4 acc0 = {0,0,0,0}, acc1 = {0,0,0,0}, acc2 = {0,0,0,0}, acc3 = {0,0,0,0};
  // region 1: k in [0,256) from prenet rows (stride 256)
  {
    const bf16* Ap = pAll + (size_t)lo*256 + hi*8;
    #pragma unroll 2
    for (int kc = 0; kc < 8; ++kc){
      int k = kc*32;
      bf16x8 bb = *(const bf16x8*)(Bp + k);
      bf16x8 a0 = *(const bf16x8*)(Ap + k);
      bf16x8 a1 = *(const bf16x8*)(Ap + 16*256 + k);
      bf16x8 a2 = *(const bf16x8*)(Ap + 32*256 + k);
      bf16x8 a3 = *(const bf16x8*)(Ap + 48*256 + k);
      acc0 = MFMA16(a0, bb, acc0);
      acc1 = MFMA16(a1, bb, acc1);
      acc2 = MFMA16(a2, bb, acc2);
      acc3 = MFMA16(a3, bb, acc3);
    }
  }
  // region 2: k in [256,1792) from Aa rows (stride 1536)
  {
    const bf16* Ap = AaR + (size_t)lo*1536 + hi*8;
    #pragma unroll 2
    for (int kc = 0; kc < 48; ++kc){
      int k = kc*32;
      bf16x8 bb = *(const bf16x8*)(Bp + 256 + k);
      bf16x8 a0 = *(const bf16x8*)(Ap + k);
      bf16x8 a1 = *(const bf16x8*)(Ap + 16*1536 + k);
      bf16x8 a2 = *(const bf16x8*)(Ap + 32*1536 + k);
      bf16x8 a3 = *(const bf16x8*)(Ap + 48*1536 + k);
      acc0 = MFMA16(a0, bb, acc0);
      acc1 = MFMA16(a1, bb, acc1);
      acc2 = MFMA16(a2, bb, acc2);
      acc3 = MFMA16(a3, bb, acc3);
    }
  }
  __shared__ float gb[64][17];
  #pragma unroll
  for (int r = 0; r < 4; ++r){
    gb[      hi*4 + r][lo] = acc0[r];
    gb[16 +  hi*4 + r][lo] = acc1[r];
    gb[32 +  hi*4 + r][lo] = acc2[r];
    gb[48 +  hi*4 + r][lo] = acc3[r];
  }
  __syncthreads();
  #pragma unroll
  for (int it = 0; it < 4; ++it){
    int item = tid + it*64;           // 0..255 : 64 batches x 4 units
    int b = item >> 2, uu = item & 3;
    int u = u0 + uu;
    float iv = gb[b][0*4 + uu] + bias[u];
    float fv = gb[b][1*4 + uu] + bias[1024 + u];
    float gv = gb[b][2*4 + uu] + bias[2048 + u];
    float ov = gb[b][3*4 + uu] + bias[3072 + u];
    float c  = sigf(fv)*cell[b*1024 + u] + sigf(iv)*tanhf_(gv);
    float h  = sigf(ov)*tanhf_(c);
    cell[b*1024 + u] = c;
    bf16 hb = (bf16)h;
    AaW_h[(size_t)b*1536 + u] = hb;
    AdR_h[(size_t)b*2560 + u] = hb;
  }
}

// ---------------- per-step: dec-LSTM gates GEMM + cell update --------------------
__global__ __launch_bounds__(64)
void dec_step(const bf16* __restrict__ AdR,    // 64 x 2560 = [ah | ctx | dh_prev]
              const bf16* __restrict__ W,      // 4096 x 2560 = [Wih_d | Whh_d]
              const float* __restrict__ bias,
              float* __restrict__ cell,        // dc
              bf16* __restrict__ AdW_dh,       // write dh: AdW + 1536 (stride 2560)
              bf16* __restrict__ projrow)      // proj_all + s*64*1536 (dh at col 0)
{
  const int tid = threadIdx.x;
  const int lo = tid & 15, hi = tid >> 4;
  const int u0 = blockIdx.x * 4;
  const int gate = lo >> 2, ur = lo & 3;
  const bf16* Bp = W + (size_t)(gate*1024 + u0 + ur)*KD + hi*8;
  const bf16* Ap = AdR + (size_t)lo*2560 + hi*8;
  f32x4 acc0 = {0,0,0,0}, acc1 = {0,0,0,0}, acc2 = {0,0,0,0}, acc3 = {0,0,0,0};
  #pragma unroll 2
  for (int kc = 0; kc < 80; ++kc){
    int k = kc*32;
    bf16x8 bb = *(const bf16x8*)(Bp + k);
    bf16x8 a0 = *(const bf16x8*)(Ap + k);
    bf16x8 a1 = *(const bf16x8*)(Ap + 16*2560 + k);
    bf16x8 a2 = *(const bf16x8*)(Ap + 32*2560 + k);
    bf16x8 a3 = *(const bf16x8*)(Ap + 48*2560 + k);
    acc0 = MFMA16(a0, bb, acc0);
    acc1 = MFMA16(a1, bb, acc1);
    acc2 = MFMA16(a2, bb, acc2);
    acc3 = MFMA16(a3, bb, acc3);
  }
  __shared__ float gb[64][17];
  #pragma unroll
  for (int r = 0; r < 4; ++r){
    gb[      hi*4 + r][lo] = acc0[r];
    gb[16 +  hi*4 + r][lo] = acc1[r];
    gb[32 +  hi*4 + r][lo] = acc2[r];
    gb[48 +  hi*4 + r][lo] = acc3[r];
  }
  __syncthreads();
  #pragma unroll
  for (int it = 0; it < 4; ++it){
    int item = tid + it*64;
    int b = item >> 2, uu = item & 3;
    int u = u0 + uu;
    float iv = gb[b][0*4 + uu] + bias[u];
    float fv = gb[b][1*4 + uu] + bias[1024 + u];
    float gv = gb[b][2*4 + uu] + bias[2048 + u];
    float ov = gb[b][3*4 + uu] + bias[3072 + u];
    float c  = sigf(fv)*cell[b*1024 + u] + sigf(iv)*tanhf_(gv);
    float h  = sigf(ov)*tanhf_(c);
    cell[b*1024 + u] = c;
    bf16 hb = (bf16)h;
    AdW_dh[(size_t)b*2560 + u]  = hb;
    projrow[(size_t)b*1536 + u] = hb;
  }
}

// ---------------- per-step: attention energies ------------------------------------
// grid (2, 64): chunk c covers t in [c*100, c*100+100); block 256 thr
__global__ __launch_bounds__(256)
void energies_kernel(const bf16* __restrict__ AaN,   // buffer with ah_s at +512
                     const bf16* __restrict__ Wq,    // 128 x 1024
                     const float* __restrict__ Wconv,// 32 x 31
                     const float* __restrict__ Wloc, // 128 x 32
                     const float* __restrict__ vv,   // 128
                     const float* __restrict__ pm,   // (64*200) x 128
                     const float* __restrict__ aw,   // 64 x 200 (prev align)
                     float* __restrict__ energ)      // 64 x 200
{
  const int b = blockIdx.y, c = blockIdx.x, tid = threadIdx.x;
  __shared__ float qv[128];
  __shared__ float qp[256];
  __shared__ float locb[100][32];
  // q = ah @ Wq^T  (each thread: half of one of 128 dims)
  {
    int a = tid & 127, hf = tid >> 7;
    const bf16* ah = AaN + (size_t)b*1536 + 512 + hf*512;
    const bf16* wr = Wq + (size_t)a*1024 + hf*512;
    float s = 0.f;
    for (int k = 0; k < 512; k += 8){
      bf16x8 x = *(const bf16x8*)(ah + k);
      bf16x8 y = *(const bf16x8*)(wr + k);
      #pragma unroll
      for (int e = 0; e < 8; ++e) s += (float)x[e]*(float)y[e];
    }
    qp[tid] = s;
  }
  __syncthreads();
  if (tid < 128) qv[tid] = qp[tid] + qp[tid + 128];
  // conv1d(31, pad 15) of previous alignment
  for (int it = tid; it < 3200; it += 256){
    int f = it & 31, tl = it >> 5;
    int t = c*100 + tl;
    float s = 0.f;
    #pragma unroll
    for (int j = 0; j < 31; ++j){
      int tt = t + j - 15;
      if ((unsigned)tt < 200u) s += aw[b*200 + tt]*Wconv[f*31 + j];
    }
    locb[tl][f] = s;
  }
  __syncthreads();
  // energies: wave per t, lanes cover 128 attn dims (2 halves)
  const int w = tid >> 6, l = tid & 63;
  for (int tl = w; tl < 100; tl += 4){
    int t = c*100 + tl;
    float s = 0.f;
    #pragma unroll
    for (int half = 0; half < 2; ++half){
      int a = l + half*64;
      float x = qv[a] + pm[((size_t)b*200 + t)*128 + a];
      const float* wl = Wloc + a*32;
      #pragma unroll
      for (int f = 0; f < 32; ++f) x += locb[tl][f]*wl[f];
      s += vv[a]*tanhf_(x);
    }
    #pragma unroll
    for (int o = 32; o; o >>= 1) s += __shfl_xor(s, o);
    if (l == 0) energ[b*200 + t] = s;
  }
}

// ---------------- per-step: softmax + context -------------------------------------
__global__ __launch_bounds__(256)
void softctx_kernel(const float* __restrict__ energ,
                    const bf16* __restrict__ enc,     // 64 x 200 x 512 bf16
                    float* __restrict__ aw,           // out: align (next conv)
                    float* __restrict__ out_attn_s,   // out + 2073600 + s*200
                    bf16* __restrict__ AaW,           // ctx -> AaW[b*1536 + d]
                    bf16* __restrict__ AdR,           // ctx -> AdR[b*2560 + 1024 + d]
                    bf16* __restrict__ projrow)       // ctx -> projrow[b*1536+1024+d]
{
  const int b = blockIdx.x, tid = threadIdx.x;
  const int w = tid >> 6, l = tid & 63;
  __shared__ float al[200];
  __shared__ float red[4];
  float e0 = (tid < 200) ? energ[b*200 + tid] : -3.0e38f;
  float m = e0;
  #pragma unroll
  for (int o = 32; o; o >>= 1) m = fmaxf(m, __shfl_xor(m, o));
  if (l == 0) red[w] = m;
  __syncthreads();
  m = fmaxf(fmaxf(red[0], red[1]), fmaxf(red[2], red[3]));
  float p = (tid < 200) ? __expf(e0 - m) : 0.f;
  float ss = p;
  #pragma unroll
  for (int o = 32; o; o >>= 1) ss += __shfl_xor(ss, o);
  __syncthreads();
  if (l == 0) red[w] = ss;
  __syncthreads();
  ss = red[0] + red[1] + red[2] + red[3];
  float a = p / ss;
  if (tid < 200){
    al[tid] = a;
    aw[b*200 + tid] = a;
    out_attn_s[(size_t)b*40000 + tid] = a;
  }
  __syncthreads();
  // ctx[d] = sum_t align[t]*enc[b,t,d]
  #pragma unroll
  for (int rep = 0; rep < 2; ++rep){
    int d = tid + rep*256;
    const bf16* ep = enc + (size_t)b*200*512 + d;
    float s = 0.f;
    #pragma unroll 4
    for (int t = 0; t < 200; ++t) s += al[t]*(float)ep[(size_t)t*512];
    bf16 cb = (bf16)s;
    AaW[(size_t)b*1536 + d]            = cb;
    AdR[(size_t)b*2560 + 1024 + d]     = cb;
    projrow[(size_t)b*1536 + 1024 + d] = cb;
  }
}

// ---------------- epilogue scatter -------------------------------------------------
__global__ void scatter_out(const float* __restrict__ mt_, float* __restrict__ out){
  int i = blockIdx.x*256 + threadIdx.x;
  const int NMEL = 12800*160;
  if (i < NMEL){
    int sb = i / 160, j = i % 160;
    int s = sb >> 6, b = sb & 63;
    int r = j / 80, mm = j % 80;
    out[((size_t)b*400 + 2*s + r)*80 + mm] = mt_[(size_t)sb*176 + j];
  } else if (i < NMEL + 12800){
    int sb = i - NMEL;
    int s = sb >> 6, b = sb & 63;
    float st = sigf(mt_[(size_t)sb*176 + 160]);
    float* so = out + 2048000;
    so[(size_t)b*400 + 2*s]     = st;
    so[(size_t)b*400 + 2*s + 1] = st;
  }
}

// ==================================================================================
extern "C" void kernel_launch(void* const* d_in, const int* in_sizes, int n_in,
                              void* d_out, int out_size, void* d_ws, size_t ws_size,
                              hipStream_t stream)
{
  const float* enc   = (const float*)d_in[0];
  const float* inp   = (const float*)d_in[1];
  const float* Wpre1 = (const float*)d_in[2];
  const float* bpre1 = (const float*)d_in[3];
  const float* Wpre2 = (const float*)d_in[4];
  const float* bpre2 = (const float*)d_in[5];
  const float* Wmem  = (const float*)d_in[6];
  const float* Wiha  = (const float*)d_in[7];
  const float* Whha  = (const float*)d_in[8];
  const float* biha  = (const float*)d_in[9];
  const float* bhha  = (const float*)d_in[10];
  const float* Wq    = (const float*)d_in[11];
  const float* Wconv = (const float*)d_in[12];
  const float* Wloc  = (const float*)d_in[13];
  const float* vv    = (const float*)d_in[14];
  const float* Wihd  = (const float*)d_in[15];
  const float* Whhd  = (const float*)d_in[16];
  const float* bihd  = (const float*)d_in[17];
  const float* bhhd  = (const float*)d_in[18];
  const float* Wmel  = (const float*)d_in[19];
  const float* bmel  = (const float*)d_in[20];
  const float* Wstop = (const float*)d_in[21];
  const float* bstop = (const float*)d_in[22];
  float* out = (float*)d_out;

  char* pp = (char*)d_ws;
  auto carve = [&](size_t bytes)->char*{
    char* r = (char*)(((uintptr_t)pp + 255) & ~(uintptr_t)255);
    pp = r + bytes;
    return r;
  };
  bf16*  enc_bf  = (bf16*) carve((size_t)64*200*512*2);
  float* pm      = (float*)carve((size_t)64*200*128*4);
  bf16*  decin   = (bf16*) carve((size_t)12800*96*2);
  bf16*  h1      = (bf16*) carve((size_t)12800*256*2);
  bf16*  pall    = (bf16*) carve((size_t)12800*256*2);
  bf16*  Wp1b    = (bf16*) carve((size_t)256*96*2);
  bf16*  Wp2b    = (bf16*) carve((size_t)256*256*2);
  bf16*  Wmemb   = (bf16*) carve((size_t)128*512*2);
  bf16*  Wqb     = (bf16*) carve((size_t)128*1024*2);
  bf16*  Wca     = (bf16*) carve((size_t)4096*KA*2);
  bf16*  Wcd     = (bf16*) carve((size_t)4096*KD*2);
  bf16*  Wmc     = (bf16*) carve((size_t)176*1536*2);
  float* biasa   = (float*)carve(4096*4);
  float* biasd   = (float*)carve(4096*4);
  float* bias176 = (float*)carve(176*4);
  bf16*  proj    = (bf16*) carve((size_t)12800*1536*2);
  float* meltmp  = (float*)carve((size_t)12800*176*4);
  float* energ   = (float*)carve(64*200*4);
  // zeroed state block (contiguous)
  bf16*  Aa0 = (bf16*) carve((size_t)64*1536*2);
  bf16*  Aa1 = (bf16*) carve((size_t)64*1536*2);
  bf16*  Ad0 = (bf16*) carve((size_t)64*2560*2);
  bf16*  Ad1 = (bf16*) carve((size_t)64*2560*2);
  float* ac  = (float*)carve((size_t)64*1024*4);
  float* dc  = (float*)carve((size_t)64*1024*4);
  float* aw  = (float*)carve((size_t)64*200*4);
  size_t zbytes = (size_t)((char*)aw + (size_t)64*200*4 - (char*)Aa0);
  hipMemsetAsync(Aa0, 0, zbytes, stream);

  // ---- prologue: conversions / packing ----
  cvt_kernel<<<(6553600+255)/256,256,0,stream>>>(enc,   enc_bf, 6553600);
  cvt_kernel<<<(131072+255)/256, 256,0,stream>>>(Wq,    Wqb,    131072);
  cvt_kernel<<<(65536+255)/256,  256,0,stream>>>(Wmem,  Wmemb,  65536);
  cvt_kernel<<<(65536+255)/256,  256,0,stream>>>(Wpre2, Wp2b,   65536);
  cvt_pad_kernel<<<(256*96+255)/256,256,0,stream>>>(Wpre1, Wp1b, 256, 80, 96);
  cat_cvt_kernel<<<(4096*KA+255)/256,256,0,stream>>>(Wiha, 768,  Whha, 1024, Wca, 4096);
  cat_cvt_kernel<<<(4096*KD+255)/256,256,0,stream>>>(Wihd, 1536, Whhd, 1024, Wcd, 4096);
  build_wmelcat<<<(176*1536+255)/256,256,0,stream>>>(Wmel, Wstop, Wmc);
  build_misc<<<(8368+255)/256,256,0,stream>>>(biha,bhha,biasa, bihd,bhhd,biasd, bmel,bstop,bias176);
  build_decin<<<(12800*96+255)/256,256,0,stream>>>(inp, decin);

  // ---- prologue: batched GEMMs ----
  // h1 = relu(decin @ Wpre1^T + b1)       M=12800 N=256 K=96
  gemm_k<1,1><<<800,256,0,stream>>>(decin, Wp1b, bpre1, nullptr, h1, 12800,256,96, 200);
  // p  = relu(h1 @ Wpre2^T + b2)          M=12800 N=256 K=256
  gemm_k<1,1><<<800,256,0,stream>>>(h1, Wp2b, bpre2, nullptr, pall, 12800,256,256, 200);
  // pm = enc @ Wmem^T                     M=12800 N=128 K=512 (f32 out)
  gemm_k<0,0><<<400,256,0,stream>>>(enc_bf, Wmemb, nullptr, pm, nullptr, 12800,128,512, 200);

  // ---- sequential scan ----
  float* out_attn = out + 2073600;
  for (int s = 0; s < STEPS; ++s){
    bf16* AaR = (s & 1) ? Aa1 : Aa0;
    bf16* AaW = (s & 1) ? Aa0 : Aa1;
    bf16* AdR = (s & 1) ? Ad1 : Ad0;
    bf16* AdW = (s & 1) ? Ad0 : Ad1;
    attn_step<<<256,64,0,stream>>>(pall + (size_t)s*64*256, AaR, Wca, biasa, ac,
                                   AaW + 512, AdR);
    energies_kernel<<<dim3(2,64),256,0,stream>>>(AaW, Wqb, Wconv, Wloc, vv, pm, aw, energ);
    softctx_kernel<<<64,256,0,stream>>>(energ, enc_bf, aw, out_attn + (size_t)s*200,
                                        AaW, AdR, proj + (size_t)s*64*1536);
    dec_step<<<256,64,0,stream>>>(AdR, Wcd, biasd, dc, AdW + 1536,
                                  proj + (size_t)s*64*1536);
  }

  // ---- epilogue: mel/stop projection + scatter ----
  gemm_k<0,0><<<550,256,0,stream>>>(proj, Wmc, bias176, meltmp, nullptr, 12800,176,1536, 200);
  scatter_out<<<(12800*160+12800+255)/256,256,0,stream>>>(meltmp, out);
}